// Round 1
// baseline (143.881 us; speedup 1.0000x reference)
//
#include <hip/hip_runtime.h>

// RankingLoss: loss = sum_{i,j} [c_i==0 && Y_j>Y_i] * relu(risk_j - risk_i) / count
// risk_i = sum(hazards[i, :4]).  B = 8192, N_CLASSES = 4, MARGIN = 0.
// Brute-force O(B^2) pair sweep, tiled through LDS. VALU-bound, ~6us floor.

#define B_SIZE 8192
#define JCHUNK 1024
#define BLOCK 256

__global__ void rl_init(float* ws) {
    ws[0] = 0.0f;                       // total (float)
    ((unsigned int*)ws)[1] = 0u;        // count (uint)
}

__global__ __launch_bounds__(BLOCK) void rl_pairs(
    const float* __restrict__ hazards,
    const int* __restrict__ Y,
    const int* __restrict__ c,
    float* __restrict__ ws)
{
    __shared__ float s_risk[JCHUNK];
    __shared__ int   s_y[JCHUNK];

    const int tid = threadIdx.x;
    const int i   = blockIdx.x * BLOCK + tid;   // row index (owns c_i, Y_i, risk_i)
    const int j0  = blockIdx.y * JCHUNK;        // column chunk base

    // Stage j-chunk (risk_j, Y_j) into LDS: 4 j's per thread.
    for (int k = tid; k < JCHUNK; k += BLOCK) {
        const int j = j0 + k;
        const float4 h = ((const float4*)hazards)[j];
        s_risk[k] = h.x + h.y + h.z + h.w;
        s_y[k]    = Y[j];
    }

    const float4 hi = ((const float4*)hazards)[i];
    const float r_i = hi.x + hi.y + hi.z + hi.w;
    const int   y_i = Y[i];
    const bool  active = (c[i] == 0);

    __syncthreads();

    float acc = 0.0f;
    int   cnt = 0;
    if (active) {
        #pragma unroll 8
        for (int k = 0; k < JCHUNK; ++k) {
            const float d = s_risk[k] - r_i;       // uniform-addr LDS read: broadcast
            const bool  m = (s_y[k] > y_i);
            acc += m ? fmaxf(d, 0.0f) : 0.0f;
            cnt += m ? 1 : 0;
        }
    }

    // wave64 reduction
    #pragma unroll
    for (int off = 32; off > 0; off >>= 1) {
        acc += __shfl_down(acc, off, 64);
        cnt += __shfl_down(cnt, off, 64);
    }

    __shared__ float s_acc[BLOCK / 64];
    __shared__ int   s_cnt[BLOCK / 64];
    const int wave = tid >> 6;
    const int lane = tid & 63;
    if (lane == 0) { s_acc[wave] = acc; s_cnt[wave] = cnt; }
    __syncthreads();

    if (tid == 0) {
        float a = 0.0f;
        int   n = 0;
        #pragma unroll
        for (int w = 0; w < BLOCK / 64; ++w) { a += s_acc[w]; n += s_cnt[w]; }
        atomicAdd(&ws[0], a);
        atomicAdd(((unsigned int*)ws) + 1, (unsigned int)n);
    }
}

__global__ void rl_final(const float* __restrict__ ws, float* __restrict__ out) {
    const unsigned int n = ((const unsigned int*)ws)[1];
    out[0] = (n > 0u) ? (ws[0] / (float)n) : 0.0f;
}

extern "C" void kernel_launch(void* const* d_in, const int* in_sizes, int n_in,
                              void* d_out, int out_size, void* d_ws, size_t ws_size,
                              hipStream_t stream) {
    const float* hazards = (const float*)d_in[0];
    // d_in[1] = S, unused by the reference computation.
    const int* Y = (const int*)d_in[2];
    const int* c = (const int*)d_in[3];
    float* ws  = (float*)d_ws;
    float* out = (float*)d_out;

    rl_init<<<1, 1, 0, stream>>>(ws);
    rl_pairs<<<dim3(B_SIZE / BLOCK, B_SIZE / JCHUNK), BLOCK, 0, stream>>>(hazards, Y, c, ws);
    rl_final<<<1, 1, 0, stream>>>(ws, out);
}

// Round 2
// 72.864 us; speedup vs baseline: 1.9747x; 1.9747x over previous
//
#include <hip/hip_runtime.h>

// RankingLoss: loss = sum_{i,j} [c_i==0 && Y_j>Y_i] * relu(risk_j - risk_i) / count
// risk = sum(hazards[:, :4], axis=1). B = 8192, N_CLASSES = 4, MARGIN = 0.
//
// R1 design: register-resident pair sweep.
//  - lane owns one j (r_j, y_j in VGPRs for entire kernel)
//  - wave holds 256 i-entries (4/lane); i broadcast via v_readlane -> SGPR
//  - censored i skipped via wave-uniform scalar branch (readlane is uniform)
//  - no LDS / no loads / no atomics in the hot loop; per-block partials to ws
//  - 2 kernels total (partials kernel needs no zero-init of ws)

#define B_SIZE 8192
#define TILE 256          // i-chunk == j-chunk == block size
#define NBLK ((B_SIZE / TILE) * (B_SIZE / TILE))   // 1024 partials

__global__ __launch_bounds__(TILE) void rl_pairs(
    const float4* __restrict__ hz,   // hazards as float4 rows [B]
    const int*    __restrict__ Y,
    const int*    __restrict__ c,
    float*        __restrict__ psum,
    int*          __restrict__ pcnt)
{
    const int tid  = threadIdx.x;
    const int lane = tid & 63;

    // ---- j side: this thread's own column, lives in registers all kernel ----
    const int j = blockIdx.x * TILE + tid;
    const float4 hj = hz[j];
    const float rj = (hj.x + hj.y) + (hj.z + hj.w);
    const int   yj = Y[j];

    // ---- i side: this wave loads the whole 256-wide i-chunk, 4 entries/lane ----
    const int i0 = blockIdx.y * TILE;
    float ri[4];
    int   yi[4];   // effective y: 1000 if censored (mask y_j > y_i never fires)
    #pragma unroll
    for (int s = 0; s < 4; ++s) {
        const int i = i0 + s * 64 + lane;
        const float4 hi = hz[i];
        ri[s] = (hi.x + hi.y) + (hi.z + hi.w);
        yi[s] = (c[i] != 0) ? 1000 : Y[i];
    }

    float acc = 0.0f;
    int   cnt = 0;
    #pragma unroll
    for (int s = 0; s < 4; ++s) {
        #pragma unroll
        for (int l = 0; l < 64; ++l) {
            const int yib = __builtin_amdgcn_readlane(yi[s], l);   // SGPR, uniform
            if (yib < 4) {   // wave-uniform scalar branch: skip censored i
                const float rib = __uint_as_float(
                    (unsigned)__builtin_amdgcn_readlane((int)__float_as_uint(ri[s]), l));
                const bool m = (yj > yib);
                const float d = fmaxf(rj - rib, 0.0f);
                acc += m ? d : 0.0f;
                cnt += m ? 1 : 0;
            }
        }
    }

    // ---- block reduction -> one partial per block ----
    #pragma unroll
    for (int off = 32; off > 0; off >>= 1) {
        acc += __shfl_down(acc, off, 64);
        cnt += __shfl_down(cnt, off, 64);
    }
    __shared__ float sa[TILE / 64];
    __shared__ int   sc[TILE / 64];
    const int wave = tid >> 6;
    if (lane == 0) { sa[wave] = acc; sc[wave] = cnt; }
    __syncthreads();
    if (tid == 0) {
        float a = 0.0f; int n = 0;
        #pragma unroll
        for (int w = 0; w < TILE / 64; ++w) { a += sa[w]; n += sc[w]; }
        const int gid = blockIdx.y * gridDim.x + blockIdx.x;
        psum[gid] = a;
        pcnt[gid] = n;
    }
}

__global__ __launch_bounds__(256) void rl_final(
    const float* __restrict__ psum,
    const int*   __restrict__ pcnt,
    float*       __restrict__ out)
{
    const int tid  = threadIdx.x;
    const int lane = tid & 63;
    float a = 0.0f; int n = 0;
    #pragma unroll
    for (int k = 0; k < NBLK / 256; ++k) {
        a += psum[k * 256 + tid];
        n += pcnt[k * 256 + tid];
    }
    #pragma unroll
    for (int off = 32; off > 0; off >>= 1) {
        a += __shfl_down(a, off, 64);
        n += __shfl_down(n, off, 64);
    }
    __shared__ float sa[4];
    __shared__ int   sc[4];
    const int wave = tid >> 6;
    if (lane == 0) { sa[wave] = a; sc[wave] = n; }
    __syncthreads();
    if (tid == 0) {
        float A = sa[0] + sa[1] + sa[2] + sa[3];
        int   N = sc[0] + sc[1] + sc[2] + sc[3];
        out[0] = (N > 0) ? (A / (float)N) : 0.0f;
    }
}

extern "C" void kernel_launch(void* const* d_in, const int* in_sizes, int n_in,
                              void* d_out, int out_size, void* d_ws, size_t ws_size,
                              hipStream_t stream) {
    const float4* hz = (const float4*)d_in[0];   // hazards [8192 x 4] f32
    // d_in[1] = S, unused by the reference computation.
    const int* Y = (const int*)d_in[2];
    const int* c = (const int*)d_in[3];
    float* psum = (float*)d_ws;                  // [1024]
    int*   pcnt = (int*)d_ws + NBLK;             // [1024]
    float* out  = (float*)d_out;

    rl_pairs<<<dim3(B_SIZE / TILE, B_SIZE / TILE), TILE, 0, stream>>>(hz, Y, c, psum, pcnt);
    rl_final<<<1, 256, 0, stream>>>(psum, pcnt, out);
}